// Round 6
// baseline (1125.780 us; speedup 1.0000x reference)
//
#include <hip/hip_runtime.h>
#include <hip/hip_bf16.h>

typedef __attribute__((ext_vector_type(8))) short bf16x8;
typedef __attribute__((ext_vector_type(4))) float f32x4;
typedef __attribute__((ext_vector_type(4))) int i32x4;

static __device__ __forceinline__ short f2bf(float f) {
    __hip_bfloat16 h = __float2bfloat16(f);
    return __builtin_bit_cast(short, h);
}
static __device__ __forceinline__ float bf2f(short s) {
    unsigned u = ((unsigned)(unsigned short)s) << 16;
    return __builtin_bit_cast(float, u);
}

static __device__ __forceinline__ void gload_lds16(const short* g, short* l) {
    __builtin_amdgcn_global_load_lds((const __attribute__((address_space(1))) void*)g,
                                     (__attribute__((address_space(3))) void*)l, 16, 0, 0);
}

// ---------------- fused weight convert: all 6 weights in one launch ----------------
__global__ void convert_all_kernel(
    const float* __restrict__ Wq, const float* __restrict__ Wk, const float* __restrict__ Wv,
    const float* __restrict__ Wo, const float* __restrict__ Win, const float* __restrict__ Wout,
    short* __restrict__ wQKV, short* __restrict__ wO, short* __restrict__ wIn, short* __restrict__ wOut)
{
    const int M1 = 1024 * 1024;
    for (int i = blockIdx.x * blockDim.x + threadIdx.x; i < 8 * M1; i += gridDim.x * blockDim.x) {
        if (i < 3 * M1) {
            float v = (i < M1) ? Wq[i] : (i < 2 * M1) ? Wk[i - M1] : Wv[i - 2 * M1];
            wQKV[i] = f2bf(v);
        } else if (i < 4 * M1) {
            wO[i - 3 * M1] = f2bf(Wo[i - 3 * M1]);
        } else if (i < 6 * M1) {
            wIn[i - 4 * M1] = f2bf(Win[i - 4 * M1]);
        } else {
            wOut[i - 6 * M1] = f2bf(Wout[i - 6 * M1]);
        }
    }
}

// ---------------- step-0: h = latents; xln = LN(latents + t0) ----------------
__global__ __launch_bounds__(256) void first_ln_kernel(
    const float* __restrict__ latents, float* __restrict__ h,
    const float* __restrict__ trow,
    const float* __restrict__ g, const float* __restrict__ bb,
    short* __restrict__ out)
{
    const int row = blockIdx.x;
    const int tid = threadIdx.x;
    const int lane = tid & 63;
    const int wid = tid >> 6;
    __shared__ float red[4];
    const float* hr = latents + (size_t)row * 1024;
    float x[4];
    float s = 0.f;
    #pragma unroll
    for (int i = 0; i < 4; ++i) {
        int c = tid + i * 256;
        float hv = hr[c];
        h[(size_t)row * 1024 + c] = hv;
        x[i] = hv + trow[c]; s += x[i];
    }
    #pragma unroll
    for (int o = 32; o >= 1; o >>= 1) s += __shfl_xor(s, o, 64);
    if (lane == 0) red[wid] = s;
    __syncthreads();
    float mean = (red[0] + red[1] + red[2] + red[3]) * (1.0f / 1024.0f);
    __syncthreads();
    float s2 = 0.f;
    #pragma unroll
    for (int i = 0; i < 4; ++i) { float d = x[i] - mean; s2 += d * d; }
    #pragma unroll
    for (int o = 32; o >= 1; o >>= 1) s2 += __shfl_xor(s2, o, 64);
    if (lane == 0) red[wid] = s2;
    __syncthreads();
    float var = (red[0] + red[1] + red[2] + red[3]) * (1.0f / 1024.0f);
    float rstd = rsqrtf(var + 1e-5f);
    #pragma unroll
    for (int i = 0; i < 4; ++i) {
        int c = tid + i * 256;
        out[(size_t)row * 1024 + c] = f2bf((x[i] - mean) * rstd * g[c] + bb[c]);
    }
}

// ---------------- layernorm (h + t_emb + add(bf16)) -> bf16 ----------------
__global__ __launch_bounds__(256) void ln_kernel(
    const float* __restrict__ hsrc, const float* __restrict__ trow,
    const short* __restrict__ add,
    const float* __restrict__ g, const float* __restrict__ bb,
    short* __restrict__ out)
{
    const int row = blockIdx.x;
    const int tid = threadIdx.x;
    const int lane = tid & 63;
    const int wid = tid >> 6;
    __shared__ float red[4];
    const float* hr = hsrc + (size_t)row * 1024;
    float x[4];
    float s = 0.f;
    #pragma unroll
    for (int i = 0; i < 4; ++i) {
        int c = tid + i * 256;
        float v = hr[c] + trow[c];
        if (add) v += bf2f(add[(size_t)row * 1024 + c]);
        x[i] = v; s += v;
    }
    #pragma unroll
    for (int o = 32; o >= 1; o >>= 1) s += __shfl_xor(s, o, 64);
    if (lane == 0) red[wid] = s;
    __syncthreads();
    float mean = (red[0] + red[1] + red[2] + red[3]) * (1.0f / 1024.0f);
    __syncthreads();
    float s2 = 0.f;
    #pragma unroll
    for (int i = 0; i < 4; ++i) { float d = x[i] - mean; s2 += d * d; }
    #pragma unroll
    for (int o = 32; o >= 1; o >>= 1) s2 += __shfl_xor(s2, o, 64);
    if (lane == 0) red[wid] = s2;
    __syncthreads();
    float var = (red[0] + red[1] + red[2] + red[3]) * (1.0f / 1024.0f);
    float rstd = rsqrtf(var + 1e-5f);
    #pragma unroll
    for (int i = 0; i < 4; ++i) {
        int c = tid + i * 256;
        out[(size_t)row * 1024 + c] = f2bf((x[i] - mean) * rstd * g[c] + bb[c]);
    }
}

// ---------------- fused clip(h += upd*scale) + LN(h_new + t_next) -> bf16 ----------------
__global__ __launch_bounds__(256) void clipln_kernel(
    const short* __restrict__ upd, float* __restrict__ h,
    const float* __restrict__ trow,
    const float* __restrict__ g, const float* __restrict__ bb,
    short* __restrict__ out)
{
    const int row = blockIdx.x;
    const int tid = threadIdx.x;
    const int lane = tid & 63;
    const int wid = tid >> 6;
    __shared__ float red[4];
    const short* ur = upd + (size_t)row * 1024;
    float u[4], hn[4];
    float s = 0.f;
    #pragma unroll
    for (int i = 0; i < 4; ++i) { u[i] = bf2f(ur[tid + i * 256]); s += u[i] * u[i]; }
    #pragma unroll
    for (int o = 32; o >= 1; o >>= 1) s += __shfl_xor(s, o, 64);
    if (lane == 0) red[wid] = s;
    __syncthreads();
    float nrm = sqrtf(red[0] + red[1] + red[2] + red[3]);
    float scale = fminf(1.0f / fmaxf(nrm, 1e-6f), 1.0f) * 0.125f;   // CLIP=1, /steps=8
    __syncthreads();
    float sm = 0.f;
    #pragma unroll
    for (int i = 0; i < 4; ++i) {
        int c = tid + i * 256;
        hn[i] = h[(size_t)row * 1024 + c] + u[i] * scale;
        h[(size_t)row * 1024 + c] = hn[i];
        hn[i] += trow[c];
        sm += hn[i];
    }
    #pragma unroll
    for (int o = 32; o >= 1; o >>= 1) sm += __shfl_xor(sm, o, 64);
    if (lane == 0) red[wid] = sm;
    __syncthreads();
    float mean = (red[0] + red[1] + red[2] + red[3]) * (1.0f / 1024.0f);
    __syncthreads();
    float s2 = 0.f;
    #pragma unroll
    for (int i = 0; i < 4; ++i) { float d = hn[i] - mean; s2 += d * d; }
    #pragma unroll
    for (int o = 32; o >= 1; o >>= 1) s2 += __shfl_xor(s2, o, 64);
    if (lane == 0) red[wid] = s2;
    __syncthreads();
    float var = (red[0] + red[1] + red[2] + red[3]) * (1.0f / 1024.0f);
    float rstd = rsqrtf(var + 1e-5f);
    #pragma unroll
    for (int i = 0; i < 4; ++i) {
        int c = tid + i * 256;
        out[(size_t)row * 1024 + c] = f2bf((hn[i] - mean) * rstd * g[c] + bb[c]);
    }
}

// ---------------- GEMM template: BMxBN tile, 64x64 per-wave, dbuf + counted vmcnt -------
// C[M][N] = act(A[M][K] @ B[N][K]^T + bias) (+ addsrc), bf16 out.
// Waves: (BM/64) x (BN/64), NT = waves*64 threads. Grid must be (N/BN, M/BM), nwg%8==0.
template<int BM, int BN, int NT, int ACT, int ADD, int BIAS>
__global__ __launch_bounds__(NT) void gemm_t(
    const short* __restrict__ A, const short* __restrict__ B,
    const float* __restrict__ bias, const short* __restrict__ addsrc,
    short* __restrict__ Cout, int M, int N, int K)
{
    const int nwg = gridDim.x * gridDim.y;
    const int orig = blockIdx.y * gridDim.x + blockIdx.x;
    const int swzid = (orig & 7) * (nwg >> 3) + (orig >> 3);
    const int bn = (swzid % gridDim.x) * BN;
    const int bm = (swzid / gridDim.x) * BM;

    __shared__ __align__(16) short As[2][BM * 64];
    __shared__ __align__(16) short Bs[2][BN * 64];
    const int tid = threadIdx.x;
    const int lane = tid & 63;
    const int wid = tid >> 6;
    const int l15 = lane & 15;
    const int l4 = lane >> 4;

    constexpr int WN = BN / 64;                      // waves along N
    const int rowbase = (wid / WN) * 64;
    const int colbase = (wid % WN) * 64;

    constexpr int SA = BM * 8;                       // 16B slots in A tile
    constexpr int SB = BN * 8;
    constexpr int AIT = (SA + NT - 1) / NT;
    constexpr int BIT = SB / NT;                     // exact for all configs used
    constexpr int LW = SA / NT + SB / NT;            // per-wave loads (min; conservative wait)

    f32x4 acc[4][4];
    #pragma unroll
    for (int m = 0; m < 4; ++m)
        #pragma unroll
        for (int n = 0; n < 4; ++n)
            acc[m][n] = (f32x4)(0.f);

    auto stage = [&](int k0, int buf) {
        #pragma unroll
        for (int i = 0; i < AIT; ++i) {
            int slot = i * NT + tid;
            if (AIT * NT == SA || slot < SA) {
                int row = slot >> 3;
                int colb = (slot & 7) * 16;
                int swz = (row & 7) << 4;
                const short* g = A + (size_t)(bm + row) * K + k0 + ((colb ^ swz) >> 1);
                gload_lds16(g, (short*)((char*)As[buf] + slot * 16));
            }
        }
        #pragma unroll
        for (int i = 0; i < BIT; ++i) {
            int slot = i * NT + tid;
            int row = slot >> 3;
            int colb = (slot & 7) * 16;
            int swz = (row & 7) << 4;
            const short* g = B + (size_t)(bn + row) * K + k0 + ((colb ^ swz) >> 1);
            gload_lds16(g, (short*)((char*)Bs[buf] + slot * 16));
        }
    };

    stage(0, 0);
    const int nt = K >> 6;
    for (int t = 0; t < nt; ++t) {
        const int cur = t & 1;
        if (t + 1 < nt) {
            stage((t + 1) << 6, cur ^ 1);
            if constexpr (LW == 5)      asm volatile("s_waitcnt vmcnt(5)" ::: "memory");
            else if constexpr (LW == 6) asm volatile("s_waitcnt vmcnt(6)" ::: "memory");
            else if constexpr (LW == 8) asm volatile("s_waitcnt vmcnt(8)" ::: "memory");
            else                        asm volatile("s_waitcnt vmcnt(4)" ::: "memory");
        } else {
            asm volatile("s_waitcnt vmcnt(0)" ::: "memory");
        }
        __builtin_amdgcn_s_barrier();
        #pragma unroll
        for (int ks = 0; ks < 2; ++ks) {
            int kb = ks * 64 + l4 * 16;
            bf16x8 a[4], b[4];
            #pragma unroll
            for (int m = 0; m < 4; ++m) {
                int row = rowbase + m * 16 + l15;
                a[m] = *(const bf16x8*)((const char*)As[cur] + row * 128 + (kb ^ ((row & 7) << 4)));
            }
            #pragma unroll
            for (int n = 0; n < 4; ++n) {
                int row = colbase + n * 16 + l15;
                b[n] = *(const bf16x8*)((const char*)Bs[cur] + row * 128 + (kb ^ ((row & 7) << 4)));
            }
            #pragma unroll
            for (int m = 0; m < 4; ++m)
                #pragma unroll
                for (int n = 0; n < 4; ++n)
                    acc[m][n] = __builtin_amdgcn_mfma_f32_16x16x32_bf16(a[m], b[n], acc[m][n], 0, 0, 0);
        }
        __builtin_amdgcn_s_barrier();
    }

    #pragma unroll
    for (int m = 0; m < 4; ++m) {
        int row = bm + rowbase + m * 16 + l4 * 4;
        #pragma unroll
        for (int n = 0; n < 4; ++n) {
            int col = bn + colbase + n * 16 + l15;
            float bv = BIAS ? bias[col] : 0.f;
            #pragma unroll
            for (int r = 0; r < 4; ++r) {
                float v = acc[m][n][r] + bv;
                if (ACT) v = v / (1.f + __expf(-v));   // silu
                if (ADD) v += bf2f(addsrc[(size_t)(row + r) * N + col]);
                Cout[(size_t)(row + r) * N + col] = f2bf(v);
            }
        }
    }
}

// ---------------- attention: one block per (b,h); S=64, HD=64 ----------------
__global__ __launch_bounds__(256) void attn_kernel(
    const short* __restrict__ qkv,   // [4096][3072] bf16 (q|k|v)
    short* __restrict__ ctx)         // [4096][1024] bf16
{
    const int blk = blockIdx.x;      // b*16 + h
    const int b = blk >> 4, hh = blk & 15;
    const int bs0 = b * 64;
    __shared__ __align__(16) short qs[64 * 64];
    __shared__ __align__(16) short ks_[64 * 64];
    __shared__ __align__(16) short vt[64 * 64];   // transposed: vt[d][j]
    __shared__ __align__(16) short ps[64 * 64];
    const int tid = threadIdx.x;
    const int lane = tid & 63;
    const int wid = tid >> 6;
    const int l15 = lane & 15;
    const int l4 = lane >> 4;

    #pragma unroll
    for (int i = 0; i < 2; ++i) {
        int slot = i * 256 + tid;    // 0..511
        int row = slot >> 3;
        int colb = (slot & 7) * 16;
        int swz = (row & 7) << 4;
        const short* gq = qkv + (size_t)(bs0 + row) * 3072 + hh * 64 + (slot & 7) * 8;
        *(i32x4*)((char*)qs + row * 128 + (colb ^ swz)) = *(const i32x4*)gq;
        const short* gk = qkv + (size_t)(bs0 + row) * 3072 + 1024 + hh * 64 + (slot & 7) * 8;
        *(i32x4*)((char*)ks_ + row * 128 + (colb ^ swz)) = *(const i32x4*)gk;
        const short* gv = qkv + (size_t)(bs0 + row) * 3072 + 2048 + hh * 64 + (slot & 7) * 8;
        i32x4 vv = *(const i32x4*)gv;
        const short* ve = (const short*)&vv;
        #pragma unroll
        for (int j = 0; j < 8; ++j) {
            int d = (slot & 7) * 8 + j;
            *(short*)((char*)vt + d * 128 + ((row * 2) ^ ((d & 7) << 4))) = ve[j];
        }
    }
    __syncthreads();

    // scores: wave wid computes rows 16*wid..+15, all 64 cols
    f32x4 sc[4];
    #pragma unroll
    for (int n = 0; n < 4; ++n) sc[n] = (f32x4)(0.f);
    #pragma unroll
    for (int ksz = 0; ksz < 2; ++ksz) {
        int kb = ksz * 64 + l4 * 16;
        int arow = wid * 16 + l15;
        bf16x8 af = *(const bf16x8*)((const char*)qs + arow * 128 + (kb ^ ((arow & 7) << 4)));
        #pragma unroll
        for (int n = 0; n < 4; ++n) {
            int brow = n * 16 + l15;
            bf16x8 bf = *(const bf16x8*)((const char*)ks_ + brow * 128 + (kb ^ ((brow & 7) << 4)));
            sc[n] = __builtin_amdgcn_mfma_f32_16x16x32_bf16(af, bf, sc[n], 0, 0, 0);
        }
    }
    // softmax over cols; lane holds rows wid*16 + l4*4 + r, cols n*16 + l15
    float sm[4];
    #pragma unroll
    for (int r = 0; r < 4; ++r) {
        float m = -1e30f;
        #pragma unroll
        for (int n = 0; n < 4; ++n) { sc[n][r] *= 0.125f; m = fmaxf(m, sc[n][r]); }
        #pragma unroll
        for (int o = 1; o < 16; o <<= 1) m = fmaxf(m, __shfl_xor(m, o, 64));
        float s = 0.f;
        #pragma unroll
        for (int n = 0; n < 4; ++n) { sc[n][r] = __expf(sc[n][r] - m); s += sc[n][r]; }
        #pragma unroll
        for (int o = 1; o < 16; o <<= 1) s += __shfl_xor(s, o, 64);
        sm[r] = 1.f / s;
    }
    #pragma unroll
    for (int n = 0; n < 4; ++n)
        #pragma unroll
        for (int r = 0; r < 4; ++r) {
            int row = wid * 16 + l4 * 4 + r;
            int col = n * 16 + l15;
            *(short*)((char*)ps + row * 128 + ((col * 2) ^ ((row & 7) << 4))) = f2bf(sc[n][r] * sm[r]);
        }
    __syncthreads();

    // out = P @ V : A = ps (k = key idx), B[k][d] = vt[d][k]
    f32x4 o[4];
    #pragma unroll
    for (int n = 0; n < 4; ++n) o[n] = (f32x4)(0.f);
    #pragma unroll
    for (int ksz = 0; ksz < 2; ++ksz) {
        int kb = ksz * 64 + l4 * 16;
        int arow = wid * 16 + l15;
        bf16x8 af = *(const bf16x8*)((const char*)ps + arow * 128 + (kb ^ ((arow & 7) << 4)));
        #pragma unroll
        for (int n = 0; n < 4; ++n) {
            int vrow = n * 16 + l15;
            bf16x8 bf = *(const bf16x8*)((const char*)vt + vrow * 128 + (kb ^ ((vrow & 7) << 4)));
            o[n] = __builtin_amdgcn_mfma_f32_16x16x32_bf16(af, bf, o[n], 0, 0, 0);
        }
    }
    #pragma unroll
    for (int n = 0; n < 4; ++n)
        #pragma unroll
        for (int r = 0; r < 4; ++r) {
            int row = wid * 16 + l4 * 4 + r;
            int col = n * 16 + l15;
            ctx[(size_t)(bs0 + row) * 1024 + hh * 64 + col] = f2bf(o[n][r]);
        }
}

// ---------------- norm clip + h update (last step, no LN fusion) ----------------
__global__ __launch_bounds__(256) void clip_kernel(const short* __restrict__ upd, float* __restrict__ h) {
    const int row = blockIdx.x;
    const int tid = threadIdx.x;
    const int lane = tid & 63;
    const int wid = tid >> 6;
    __shared__ float red[4];
    const short* ur = upd + (size_t)row * 1024;
    float x[4];
    float s = 0.f;
    #pragma unroll
    for (int i = 0; i < 4; ++i) { x[i] = bf2f(ur[tid + i * 256]); s += x[i] * x[i]; }
    #pragma unroll
    for (int o = 32; o >= 1; o >>= 1) s += __shfl_xor(s, o, 64);
    if (lane == 0) red[wid] = s;
    __syncthreads();
    float nrm = sqrtf(red[0] + red[1] + red[2] + red[3]);
    float unorm = fmaxf(nrm, 1e-6f);
    float scale = fminf(1.0f / unorm, 1.0f) * 0.125f;   // CLIP=1, /steps=8
    #pragma unroll
    for (int i = 0; i < 4; ++i) {
        int c = tid + i * 256;
        h[(size_t)row * 1024 + c] += x[i] * scale;
    }
}

extern "C" void kernel_launch(void* const* d_in, const int* in_sizes, int n_in,
                              void* d_out, int out_size, void* d_ws, size_t ws_size,
                              hipStream_t stream) {
    const float* latents = (const float*)d_in[0];
    const float* t_table = (const float*)d_in[1];
    const float* attn_g  = (const float*)d_in[2];
    const float* attn_b  = (const float*)d_in[3];
    const float* ffn_g   = (const float*)d_in[4];
    const float* ffn_b   = (const float*)d_in[5];
    const float* Wq      = (const float*)d_in[6];
    const float* Wk      = (const float*)d_in[7];
    const float* Wv      = (const float*)d_in[8];
    const float* Wo      = (const float*)d_in[9];
    const float* Win     = (const float*)d_in[10];
    const float* b_in    = (const float*)d_in[11];
    const float* Wout    = (const float*)d_in[12];
    const float* b_out   = (const float*)d_in[13];

    char* ws = (char*)d_ws;
    size_t off = 0;
    auto alloc = [&](size_t bytes) { char* p = ws + off; off += (bytes + 255) & ~(size_t)255; return p; };
    short* wQKV = (short*)alloc((size_t)3072 * 1024 * 2);
    short* wO   = (short*)alloc((size_t)1024 * 1024 * 2);
    short* wIn  = (short*)alloc((size_t)2048 * 1024 * 2);
    short* wOut = (short*)alloc((size_t)1024 * 2048 * 2);
    short* xln  = (short*)alloc((size_t)4096 * 1024 * 2);
    short* qkv  = (short*)alloc((size_t)4096 * 3072 * 2);
    short* hidden = qkv;  // alias: qkv dead after attention, hidden born after
    short* ctx  = (short*)alloc((size_t)4096 * 1024 * 2);
    short* au   = (short*)alloc((size_t)4096 * 1024 * 2);   // bf16
    short* upd  = (short*)alloc((size_t)4096 * 1024 * 2);   // bf16

    float* h = (float*)d_out;   // h lives in d_out

    // all weights -> bf16 in one launch
    convert_all_kernel<<<2048, 256, 0, stream>>>(Wq, Wk, Wv, Wo, Win, Wout, wQKV, wO, wIn, wOut);
    // h = latents; xln = LN(latents + t0)
    first_ln_kernel<<<4096, 256, 0, stream>>>(latents, h, t_table, attn_g, attn_b, xln);

    for (int step = 0; step < 8; ++step) {
        const float* trow = t_table + (size_t)step * 1024;   // step <= 7 < T_EMB-1=8
        // qkv = xln @ WqkvT  [128x384, 12 waves, grid 8x32=256]
        gemm_t<128, 384, 768, 0, 0, 0><<<dim3(8, 32), 768, 0, stream>>>(xln, wQKV, nullptr, nullptr, qkv, 4096, 3072, 1024);
        // attention -> ctx
        attn_kernel<<<1024, 256, 0, stream>>>(qkv, ctx);
        // attn_update = ctx @ WoT -> au (bf16)  [128x128, 4 waves, grid 8x32=256]
        gemm_t<128, 128, 256, 0, 0, 0><<<dim3(8, 32), 256, 0, stream>>>(ctx, wO, nullptr, nullptr, au, 4096, 1024, 1024);
        // ffn_in = LN(h + t + au) -> xln (bf16, reuse)
        ln_kernel<<<4096, 256, 0, stream>>>(h, trow, au, ffn_g, ffn_b, xln);
        // hidden = silu(xln @ WinT + b_in) (bf16)  [128x256, 8 waves, grid 8x32=256]
        gemm_t<128, 256, 512, 1, 0, 1><<<dim3(8, 32), 512, 0, stream>>>(xln, wIn, b_in, nullptr, hidden, 4096, 2048, 1024);
        // upd = hidden @ WoutT + b_out + au (bf16)  [128x128, 4 waves, grid 8x32=256]
        gemm_t<128, 128, 256, 0, 1, 1><<<dim3(8, 32), 256, 0, stream>>>(hidden, wOut, b_out, au, upd, 4096, 1024, 2048);
        if (step < 7) {
            // h += clip(upd)/8, then LN1 of next step -> xln
            clipln_kernel<<<4096, 256, 0, stream>>>(upd, h, t_table + (size_t)(step + 1) * 1024,
                                                    attn_g, attn_b, xln);
        } else {
            clip_kernel<<<4096, 256, 0, stream>>>(upd, h);
        }
    }
}

// Round 7
// 1062.483 us; speedup vs baseline: 1.0596x; 1.0596x over previous
//
#include <hip/hip_runtime.h>
#include <hip/hip_bf16.h>

typedef __attribute__((ext_vector_type(8))) short bf16x8;
typedef __attribute__((ext_vector_type(4))) float f32x4;
typedef __attribute__((ext_vector_type(4))) int i32x4;

static __device__ __forceinline__ short f2bf(float f) {
    __hip_bfloat16 h = __float2bfloat16(f);
    return __builtin_bit_cast(short, h);
}
static __device__ __forceinline__ float bf2f(short s) {
    unsigned u = ((unsigned)(unsigned short)s) << 16;
    return __builtin_bit_cast(float, u);
}

static __device__ __forceinline__ void gload_lds16(const short* g, short* l) {
    __builtin_amdgcn_global_load_lds((const __attribute__((address_space(1))) void*)g,
                                     (__attribute__((address_space(3))) void*)l, 16, 0, 0);
}

// ---------------- fused weight convert: all 6 weights in one launch ----------------
__global__ void convert_all_kernel(
    const float* __restrict__ Wq, const float* __restrict__ Wk, const float* __restrict__ Wv,
    const float* __restrict__ Wo, const float* __restrict__ Win, const float* __restrict__ Wout,
    short* __restrict__ wQKV, short* __restrict__ wO, short* __restrict__ wIn, short* __restrict__ wOut)
{
    const int M1 = 1024 * 1024;
    for (int i = blockIdx.x * blockDim.x + threadIdx.x; i < 8 * M1; i += gridDim.x * blockDim.x) {
        if (i < 3 * M1) {
            float v = (i < M1) ? Wq[i] : (i < 2 * M1) ? Wk[i - M1] : Wv[i - 2 * M1];
            wQKV[i] = f2bf(v);
        } else if (i < 4 * M1) {
            wO[i - 3 * M1] = f2bf(Wo[i - 3 * M1]);
        } else if (i < 6 * M1) {
            wIn[i - 4 * M1] = f2bf(Win[i - 4 * M1]);
        } else {
            wOut[i - 6 * M1] = f2bf(Wout[i - 6 * M1]);
        }
    }
}

// ---------------- step-0: h = latents; xln = LN(latents + t0) ----------------
__global__ __launch_bounds__(256) void first_ln_kernel(
    const float* __restrict__ latents, float* __restrict__ h,
    const float* __restrict__ trow,
    const float* __restrict__ g, const float* __restrict__ bb,
    short* __restrict__ out)
{
    const int row = blockIdx.x;
    const int tid = threadIdx.x;
    const int lane = tid & 63;
    const int wid = tid >> 6;
    __shared__ float red[4];
    const float* hr = latents + (size_t)row * 1024;
    float x[4];
    float s = 0.f;
    #pragma unroll
    for (int i = 0; i < 4; ++i) {
        int c = tid + i * 256;
        float hv = hr[c];
        h[(size_t)row * 1024 + c] = hv;
        x[i] = hv + trow[c]; s += x[i];
    }
    #pragma unroll
    for (int o = 32; o >= 1; o >>= 1) s += __shfl_xor(s, o, 64);
    if (lane == 0) red[wid] = s;
    __syncthreads();
    float mean = (red[0] + red[1] + red[2] + red[3]) * (1.0f / 1024.0f);
    __syncthreads();
    float s2 = 0.f;
    #pragma unroll
    for (int i = 0; i < 4; ++i) { float d = x[i] - mean; s2 += d * d; }
    #pragma unroll
    for (int o = 32; o >= 1; o >>= 1) s2 += __shfl_xor(s2, o, 64);
    if (lane == 0) red[wid] = s2;
    __syncthreads();
    float var = (red[0] + red[1] + red[2] + red[3]) * (1.0f / 1024.0f);
    float rstd = rsqrtf(var + 1e-5f);
    #pragma unroll
    for (int i = 0; i < 4; ++i) {
        int c = tid + i * 256;
        out[(size_t)row * 1024 + c] = f2bf((x[i] - mean) * rstd * g[c] + bb[c]);
    }
}

// ---------------- layernorm (h + t_emb + add(bf16)) -> bf16 ----------------
__global__ __launch_bounds__(256) void ln_kernel(
    const float* __restrict__ hsrc, const float* __restrict__ trow,
    const short* __restrict__ add,
    const float* __restrict__ g, const float* __restrict__ bb,
    short* __restrict__ out)
{
    const int row = blockIdx.x;
    const int tid = threadIdx.x;
    const int lane = tid & 63;
    const int wid = tid >> 6;
    __shared__ float red[4];
    const float* hr = hsrc + (size_t)row * 1024;
    float x[4];
    float s = 0.f;
    #pragma unroll
    for (int i = 0; i < 4; ++i) {
        int c = tid + i * 256;
        float v = hr[c] + trow[c];
        if (add) v += bf2f(add[(size_t)row * 1024 + c]);
        x[i] = v; s += v;
    }
    #pragma unroll
    for (int o = 32; o >= 1; o >>= 1) s += __shfl_xor(s, o, 64);
    if (lane == 0) red[wid] = s;
    __syncthreads();
    float mean = (red[0] + red[1] + red[2] + red[3]) * (1.0f / 1024.0f);
    __syncthreads();
    float s2 = 0.f;
    #pragma unroll
    for (int i = 0; i < 4; ++i) { float d = x[i] - mean; s2 += d * d; }
    #pragma unroll
    for (int o = 32; o >= 1; o >>= 1) s2 += __shfl_xor(s2, o, 64);
    if (lane == 0) red[wid] = s2;
    __syncthreads();
    float var = (red[0] + red[1] + red[2] + red[3]) * (1.0f / 1024.0f);
    float rstd = rsqrtf(var + 1e-5f);
    #pragma unroll
    for (int i = 0; i < 4; ++i) {
        int c = tid + i * 256;
        out[(size_t)row * 1024 + c] = f2bf((x[i] - mean) * rstd * g[c] + bb[c]);
    }
}

// ---------------- fused clip(h += upd*scale) + LN(h_new + t_next) -> bf16 ----------------
__global__ __launch_bounds__(256) void clipln_kernel(
    const short* __restrict__ upd, float* __restrict__ h,
    const float* __restrict__ trow,
    const float* __restrict__ g, const float* __restrict__ bb,
    short* __restrict__ out)
{
    const int row = blockIdx.x;
    const int tid = threadIdx.x;
    const int lane = tid & 63;
    const int wid = tid >> 6;
    __shared__ float red[4];
    const short* ur = upd + (size_t)row * 1024;
    float u[4], hn[4];
    float s = 0.f;
    #pragma unroll
    for (int i = 0; i < 4; ++i) { u[i] = bf2f(ur[tid + i * 256]); s += u[i] * u[i]; }
    #pragma unroll
    for (int o = 32; o >= 1; o >>= 1) s += __shfl_xor(s, o, 64);
    if (lane == 0) red[wid] = s;
    __syncthreads();
    float nrm = sqrtf(red[0] + red[1] + red[2] + red[3]);
    float scale = fminf(1.0f / fmaxf(nrm, 1e-6f), 1.0f) * 0.125f;   // CLIP=1, /steps=8
    __syncthreads();
    float sm = 0.f;
    #pragma unroll
    for (int i = 0; i < 4; ++i) {
        int c = tid + i * 256;
        hn[i] = h[(size_t)row * 1024 + c] + u[i] * scale;
        h[(size_t)row * 1024 + c] = hn[i];
        hn[i] += trow[c];
        sm += hn[i];
    }
    #pragma unroll
    for (int o = 32; o >= 1; o >>= 1) sm += __shfl_xor(sm, o, 64);
    if (lane == 0) red[wid] = sm;
    __syncthreads();
    float mean = (red[0] + red[1] + red[2] + red[3]) * (1.0f / 1024.0f);
    __syncthreads();
    float s2 = 0.f;
    #pragma unroll
    for (int i = 0; i < 4; ++i) { float d = hn[i] - mean; s2 += d * d; }
    #pragma unroll
    for (int o = 32; o >= 1; o >>= 1) s2 += __shfl_xor(s2, o, 64);
    if (lane == 0) red[wid] = s2;
    __syncthreads();
    float var = (red[0] + red[1] + red[2] + red[3]) * (1.0f / 1024.0f);
    float rstd = rsqrtf(var + 1e-5f);
    #pragma unroll
    for (int i = 0; i < 4; ++i) {
        int c = tid + i * 256;
        out[(size_t)row * 1024 + c] = f2bf((hn[i] - mean) * rstd * g[c] + bb[c]);
    }
}

// ---------------- GEMM: C[M][N] = act(A[M][K] @ B[N][K]^T + bias) (+ addsrc bf16) ----------
// BMx128 tile, BK=64, 8 waves (512 thr) — the round-4 proven configs.
// BM=128: waves 4Mx2N (32x64 each, MF=2 NF=4). BM=64: waves 2Mx4N (32x32, MF=2 NF=2).
// 1-barrier-per-tile schedule (T3-minimum): stage(t+1) issued BEFORE ds_read+MFMA of
// tile t; single vmcnt(0)+barrier after the MFMA cluster. Safe: all waves' ds_reads of
// buf[cur] are consumed (lgkm-drained) before the barrier, so re-staging buf[cur] at
// t+1 cannot race; vmcnt(0)+barrier makes tile-(t+1) data visible for the next reads.
template<int BM, int ACT, int ADD, int BIAS>
__global__ __launch_bounds__(512) void gemm_kernel(
    const short* __restrict__ A, const short* __restrict__ B,
    const float* __restrict__ bias, const short* __restrict__ addsrc,
    short* __restrict__ Cout, int M, int N, int K)
{
    // XCD-chunked bijective block swizzle (all grids %8==0)
    const int nwg = gridDim.x * gridDim.y;
    const int orig = blockIdx.y * gridDim.x + blockIdx.x;
    const int swzid = (orig & 7) * (nwg >> 3) + (orig >> 3);
    const int bn = (swzid % gridDim.x) * 128;
    const int bm = (swzid / gridDim.x) * BM;

    __shared__ __align__(16) short As[2][BM * 64];
    __shared__ __align__(16) short Bs[2][128 * 64];
    const int tid = threadIdx.x;
    const int lane = tid & 63;
    const int wid = tid >> 6;           // 0..7
    const int l15 = lane & 15;
    const int l4 = lane >> 4;

    constexpr int MF = 2;
    constexpr int NF = (BM == 128) ? 4 : 2;
    const int rowbase = (BM == 128) ? (wid >> 1) * 32 : (wid >> 2) * 32;
    const int colbase = (BM == 128) ? (wid & 1) * 64 : (wid & 3) * 32;

    constexpr int ALOADS = BM * 8 / 512;            // 2 (BM=128) or 1 (BM=64)

    f32x4 acc[MF][NF];
    #pragma unroll
    for (int m = 0; m < MF; ++m)
        #pragma unroll
        for (int n = 0; n < NF; ++n)
            acc[m][n] = (f32x4)(0.f);

    auto stage = [&](int k0, int buf) {
        #pragma unroll
        for (int i = 0; i < ALOADS; ++i) {
            int slot = i * 512 + tid;
            int row = slot >> 3;
            int colb = (slot & 7) * 16;
            int swz = (row & 7) << 4;
            const short* g = A + (size_t)(bm + row) * K + k0 + ((colb ^ swz) >> 1);
            gload_lds16(g, (short*)((char*)As[buf] + slot * 16));
        }
        #pragma unroll
        for (int i = 0; i < 2; ++i) {
            int slot = i * 512 + tid;
            int row = slot >> 3;
            int colb = (slot & 7) * 16;
            int swz = (row & 7) << 4;
            const short* g = B + (size_t)(bn + row) * K + k0 + ((colb ^ swz) >> 1);
            gload_lds16(g, (short*)((char*)Bs[buf] + slot * 16));
        }
    };

    // prologue: tile 0 staged and made visible
    stage(0, 0);
    asm volatile("s_waitcnt vmcnt(0)" ::: "memory");
    __builtin_amdgcn_s_barrier();

    const int nt = K >> 6;
    for (int t = 0; t < nt; ++t) {
        const int cur = t & 1;
        if (t + 1 < nt) stage((t + 1) << 6, cur ^ 1);   // in flight under ds_read+MFMA
        #pragma unroll
        for (int ks = 0; ks < 2; ++ks) {
            int kb = ks * 64 + l4 * 16;
            bf16x8 a[MF], b[NF];
            #pragma unroll
            for (int m = 0; m < MF; ++m) {
                int row = rowbase + m * 16 + l15;
                a[m] = *(const bf16x8*)((const char*)As[cur] + row * 128 + (kb ^ ((row & 7) << 4)));
            }
            #pragma unroll
            for (int n = 0; n < NF; ++n) {
                int row = colbase + n * 16 + l15;
                b[n] = *(const bf16x8*)((const char*)Bs[cur] + row * 128 + (kb ^ ((row & 7) << 4)));
            }
            #pragma unroll
            for (int m = 0; m < MF; ++m)
                #pragma unroll
                for (int n = 0; n < NF; ++n)
                    acc[m][n] = __builtin_amdgcn_mfma_f32_16x16x32_bf16(a[m], b[n], acc[m][n], 0, 0, 0);
        }
        if (t + 1 < nt) {
            asm volatile("s_waitcnt vmcnt(0)" ::: "memory");   // tile-(t+1) landed
            __builtin_amdgcn_s_barrier();                      // visible; cur free to re-stage
        }
    }

    #pragma unroll
    for (int m = 0; m < MF; ++m) {
        int row = bm + rowbase + m * 16 + l4 * 4;
        #pragma unroll
        for (int n = 0; n < NF; ++n) {
            int col = bn + colbase + n * 16 + l15;
            float bv = BIAS ? bias[col] : 0.f;
            #pragma unroll
            for (int r = 0; r < 4; ++r) {
                float v = acc[m][n][r] + bv;
                if (ACT) v = v / (1.f + __expf(-v));   // silu
                if (ADD) v += bf2f(addsrc[(size_t)(row + r) * N + col]);
                Cout[(size_t)(row + r) * N + col] = f2bf(v);
            }
        }
    }
}

// ---------------- attention: one block per (b,h); S=64, HD=64 ----------------
__global__ __launch_bounds__(256) void attn_kernel(
    const short* __restrict__ qkv,   // [4096][3072] bf16 (q|k|v)
    short* __restrict__ ctx)         // [4096][1024] bf16
{
    const int blk = blockIdx.x;      // b*16 + h
    const int b = blk >> 4, hh = blk & 15;
    const int bs0 = b * 64;
    __shared__ __align__(16) short qs[64 * 64];
    __shared__ __align__(16) short ks_[64 * 64];
    __shared__ __align__(16) short vt[64 * 64];   // transposed: vt[d][j]
    __shared__ __align__(16) short ps[64 * 64];
    const int tid = threadIdx.x;
    const int lane = tid & 63;
    const int wid = tid >> 6;
    const int l15 = lane & 15;
    const int l4 = lane >> 4;

    #pragma unroll
    for (int i = 0; i < 2; ++i) {
        int slot = i * 256 + tid;    // 0..511
        int row = slot >> 3;
        int colb = (slot & 7) * 16;
        int swz = (row & 7) << 4;
        const short* gq = qkv + (size_t)(bs0 + row) * 3072 + hh * 64 + (slot & 7) * 8;
        *(i32x4*)((char*)qs + row * 128 + (colb ^ swz)) = *(const i32x4*)gq;
        const short* gk = qkv + (size_t)(bs0 + row) * 3072 + 1024 + hh * 64 + (slot & 7) * 8;
        *(i32x4*)((char*)ks_ + row * 128 + (colb ^ swz)) = *(const i32x4*)gk;
        const short* gv = qkv + (size_t)(bs0 + row) * 3072 + 2048 + hh * 64 + (slot & 7) * 8;
        i32x4 vv = *(const i32x4*)gv;
        const short* ve = (const short*)&vv;
        #pragma unroll
        for (int j = 0; j < 8; ++j) {
            int d = (slot & 7) * 8 + j;
            *(short*)((char*)vt + d * 128 + ((row * 2) ^ ((d & 7) << 4))) = ve[j];
        }
    }
    __syncthreads();

    // scores: wave wid computes rows 16*wid..+15, all 64 cols
    f32x4 sc[4];
    #pragma unroll
    for (int n = 0; n < 4; ++n) sc[n] = (f32x4)(0.f);
    #pragma unroll
    for (int ksz = 0; ksz < 2; ++ksz) {
        int kb = ksz * 64 + l4 * 16;
        int arow = wid * 16 + l15;
        bf16x8 af = *(const bf16x8*)((const char*)qs + arow * 128 + (kb ^ ((arow & 7) << 4)));
        #pragma unroll
        for (int n = 0; n < 4; ++n) {
            int brow = n * 16 + l15;
            bf16x8 bf = *(const bf16x8*)((const char*)ks_ + brow * 128 + (kb ^ ((brow & 7) << 4)));
            sc[n] = __builtin_amdgcn_mfma_f32_16x16x32_bf16(af, bf, sc[n], 0, 0, 0);
        }
    }
    // softmax over cols; lane holds rows wid*16 + l4*4 + r, cols n*16 + l15
    float sm[4];
    #pragma unroll
    for (int r = 0; r < 4; ++r) {
        float m = -1e30f;
        #pragma unroll
        for (int n = 0; n < 4; ++n) { sc[n][r] *= 0.125f; m = fmaxf(m, sc[n][r]); }
        #pragma unroll
        for (int o = 1; o < 16; o <<= 1) m = fmaxf(m, __shfl_xor(m, o, 64));
        float s = 0.f;
        #pragma unroll
        for (int n = 0; n < 4; ++n) { sc[n][r] = __expf(sc[n][r] - m); s += sc[n][r]; }
        #pragma unroll
        for (int o = 1; o < 16; o <<= 1) s += __shfl_xor(s, o, 64);
        sm[r] = 1.f / s;
    }
    #pragma unroll
    for (int n = 0; n < 4; ++n)
        #pragma unroll
        for (int r = 0; r < 4; ++r) {
            int row = wid * 16 + l4 * 4 + r;
            int col = n * 16 + l15;
            *(short*)((char*)ps + row * 128 + ((col * 2) ^ ((row & 7) << 4))) = f2bf(sc[n][r] * sm[r]);
        }
    __syncthreads();

    // out = P @ V : A = ps (k = key idx), B[k][d] = vt[d][k]
    f32x4 o[4];
    #pragma unroll
    for (int n = 0; n < 4; ++n) o[n] = (f32x4)(0.f);
    #pragma unroll
    for (int ksz = 0; ksz < 2; ++ksz) {
        int kb = ksz * 64 + l4 * 16;
        int arow = wid * 16 + l15;
        bf16x8 af = *(const bf16x8*)((const char*)ps + arow * 128 + (kb ^ ((arow & 7) << 4)));
        #pragma unroll
        for (int n = 0; n < 4; ++n) {
            int vrow = n * 16 + l15;
            bf16x8 bf = *(const bf16x8*)((const char*)vt + vrow * 128 + (kb ^ ((vrow & 7) << 4)));
            o[n] = __builtin_amdgcn_mfma_f32_16x16x32_bf16(af, bf, o[n], 0, 0, 0);
        }
    }
    #pragma unroll
    for (int n = 0; n < 4; ++n)
        #pragma unroll
        for (int r = 0; r < 4; ++r) {
            int row = wid * 16 + l4 * 4 + r;
            int col = n * 16 + l15;
            ctx[(size_t)(bs0 + row) * 1024 + hh * 64 + col] = f2bf(o[n][r]);
        }
}

// ---------------- norm clip + h update (last step, no LN fusion) ----------------
__global__ __launch_bounds__(256) void clip_kernel(const short* __restrict__ upd, float* __restrict__ h) {
    const int row = blockIdx.x;
    const int tid = threadIdx.x;
    const int lane = tid & 63;
    const int wid = tid >> 6;
    __shared__ float red[4];
    const short* ur = upd + (size_t)row * 1024;
    float x[4];
    float s = 0.f;
    #pragma unroll
    for (int i = 0; i < 4; ++i) { x[i] = bf2f(ur[tid + i * 256]); s += x[i] * x[i]; }
    #pragma unroll
    for (int o = 32; o >= 1; o >>= 1) s += __shfl_xor(s, o, 64);
    if (lane == 0) red[wid] = s;
    __syncthreads();
    float nrm = sqrtf(red[0] + red[1] + red[2] + red[3]);
    float unorm = fmaxf(nrm, 1e-6f);
    float scale = fminf(1.0f / unorm, 1.0f) * 0.125f;   // CLIP=1, /steps=8
    #pragma unroll
    for (int i = 0; i < 4; ++i) {
        int c = tid + i * 256;
        h[(size_t)row * 1024 + c] += x[i] * scale;
    }
}

extern "C" void kernel_launch(void* const* d_in, const int* in_sizes, int n_in,
                              void* d_out, int out_size, void* d_ws, size_t ws_size,
                              hipStream_t stream) {
    const float* latents = (const float*)d_in[0];
    const float* t_table = (const float*)d_in[1];
    const float* attn_g  = (const float*)d_in[2];
    const float* attn_b  = (const float*)d_in[3];
    const float* ffn_g   = (const float*)d_in[4];
    const float* ffn_b   = (const float*)d_in[5];
    const float* Wq      = (const float*)d_in[6];
    const float* Wk      = (const float*)d_in[7];
    const float* Wv      = (const float*)d_in[8];
    const float* Wo      = (const float*)d_in[9];
    const float* Win     = (const float*)d_in[10];
    const float* b_in    = (const float*)d_in[11];
    const float* Wout    = (const float*)d_in[12];
    const float* b_out   = (const float*)d_in[13];

    char* ws = (char*)d_ws;
    size_t off = 0;
    auto alloc = [&](size_t bytes) { char* p = ws + off; off += (bytes + 255) & ~(size_t)255; return p; };
    short* wQKV = (short*)alloc((size_t)3072 * 1024 * 2);
    short* wO   = (short*)alloc((size_t)1024 * 1024 * 2);
    short* wIn  = (short*)alloc((size_t)2048 * 1024 * 2);
    short* wOut = (short*)alloc((size_t)1024 * 2048 * 2);
    short* xln  = (short*)alloc((size_t)4096 * 1024 * 2);
    short* qkv  = (short*)alloc((size_t)4096 * 3072 * 2);
    short* hidden = qkv;  // alias: qkv dead after attention, hidden born after
    short* ctx  = (short*)alloc((size_t)4096 * 1024 * 2);
    short* au   = (short*)alloc((size_t)4096 * 1024 * 2);   // bf16
    short* upd  = (short*)alloc((size_t)4096 * 1024 * 2);   // bf16

    float* h = (float*)d_out;   // h lives in d_out

    // all weights -> bf16 in one launch
    convert_all_kernel<<<2048, 256, 0, stream>>>(Wq, Wk, Wv, Wo, Win, Wout, wQKV, wO, wIn, wOut);
    // h = latents; xln = LN(latents + t0)
    first_ln_kernel<<<4096, 256, 0, stream>>>(latents, h, t_table, attn_g, attn_b, xln);

    for (int step = 0; step < 8; ++step) {
        const float* trow = t_table + (size_t)step * 1024;   // step <= 7 < T_EMB-1=8
        // qkv = xln @ WqkvT  [R4 config: BM=128, 8 waves, grid 24x32=768]
        gemm_kernel<128, 0, 0, 0><<<dim3(24, 32), 512, 0, stream>>>(xln, wQKV, nullptr, nullptr, qkv, 4096, 3072, 1024);
        // attention -> ctx
        attn_kernel<<<1024, 256, 0, stream>>>(qkv, ctx);
        // attn_update = ctx @ WoT -> au (bf16)  [R4 config: BM=64, grid 8x64=512]
        gemm_kernel<64, 0, 0, 0><<<dim3(8, 64), 512, 0, stream>>>(ctx, wO, nullptr, nullptr, au, 4096, 1024, 1024);
        // ffn_in = LN(h + t + au) -> xln (bf16, reuse)
        ln_kernel<<<4096, 256, 0, stream>>>(h, trow, au, ffn_g, ffn_b, xln);
        // hidden = silu(xln @ WinT + b_in) (bf16)  [R4 config: BM=128, grid 16x32=512]
        gemm_kernel<128, 1, 0, 1><<<dim3(16, 32), 512, 0, stream>>>(xln, wIn, b_in, nullptr, hidden, 4096, 2048, 1024);
        // upd = hidden @ WoutT + b_out + au (bf16)  [R4 config: BM=64, grid 8x64=512]
        gemm_kernel<64, 0, 1, 1><<<dim3(8, 64), 512, 0, stream>>>(hidden, wOut, b_out, au, upd, 4096, 1024, 2048);
        if (step < 7) {
            // h += clip(upd)/8, then LN1 of next step -> xln
            clipln_kernel<<<4096, 256, 0, stream>>>(upd, h, t_table + (size_t)(step + 1) * 1024,
                                                    attn_g, attn_b, xln);
        } else {
            clip_kernel<<<4096, 256, 0, stream>>>(upd, h);
        }
    }
}

// Round 8
// 1039.723 us; speedup vs baseline: 1.0828x; 1.0219x over previous
//
#include <hip/hip_runtime.h>
#include <hip/hip_bf16.h>

typedef __attribute__((ext_vector_type(8))) short bf16x8;
typedef __attribute__((ext_vector_type(4))) float f32x4;
typedef __attribute__((ext_vector_type(4))) int i32x4;

static __device__ __forceinline__ short f2bf(float f) {
    __hip_bfloat16 h = __float2bfloat16(f);
    return __builtin_bit_cast(short, h);
}
static __device__ __forceinline__ float bf2f(short s) {
    unsigned u = ((unsigned)(unsigned short)s) << 16;
    return __builtin_bit_cast(float, u);
}

static __device__ __forceinline__ void gload_lds16(const short* g, short* l) {
    __builtin_amdgcn_global_load_lds((const __attribute__((address_space(1))) void*)g,
                                     (__attribute__((address_space(3))) void*)l, 16, 0, 0);
}

// ---------------- fused weight convert: all 6 weights in one launch ----------------
__global__ void convert_all_kernel(
    const float* __restrict__ Wq, const float* __restrict__ Wk, const float* __restrict__ Wv,
    const float* __restrict__ Wo, const float* __restrict__ Win, const float* __restrict__ Wout,
    short* __restrict__ wQKV, short* __restrict__ wO, short* __restrict__ wIn, short* __restrict__ wOut)
{
    const int M1 = 1024 * 1024;
    for (int i = blockIdx.x * blockDim.x + threadIdx.x; i < 8 * M1; i += gridDim.x * blockDim.x) {
        if (i < 3 * M1) {
            float v = (i < M1) ? Wq[i] : (i < 2 * M1) ? Wk[i - M1] : Wv[i - 2 * M1];
            wQKV[i] = f2bf(v);
        } else if (i < 4 * M1) {
            wO[i - 3 * M1] = f2bf(Wo[i - 3 * M1]);
        } else if (i < 6 * M1) {
            wIn[i - 4 * M1] = f2bf(Win[i - 4 * M1]);
        } else {
            wOut[i - 6 * M1] = f2bf(Wout[i - 6 * M1]);
        }
    }
}

// ---------------- step-0: h = latents; xln = LN(latents + t0) ----------------
__global__ __launch_bounds__(256) void first_ln_kernel(
    const float* __restrict__ latents, float* __restrict__ h,
    const float* __restrict__ trow,
    const float* __restrict__ g, const float* __restrict__ bb,
    short* __restrict__ out)
{
    const int row = blockIdx.x;
    const int tid = threadIdx.x;
    const int lane = tid & 63;
    const int wid = tid >> 6;
    __shared__ float red[4];
    const float* hr = latents + (size_t)row * 1024;
    float x[4];
    float s = 0.f;
    #pragma unroll
    for (int i = 0; i < 4; ++i) {
        int c = tid + i * 256;
        float hv = hr[c];
        h[(size_t)row * 1024 + c] = hv;
        x[i] = hv + trow[c]; s += x[i];
    }
    #pragma unroll
    for (int o = 32; o >= 1; o >>= 1) s += __shfl_xor(s, o, 64);
    if (lane == 0) red[wid] = s;
    __syncthreads();
    float mean = (red[0] + red[1] + red[2] + red[3]) * (1.0f / 1024.0f);
    __syncthreads();
    float s2 = 0.f;
    #pragma unroll
    for (int i = 0; i < 4; ++i) { float d = x[i] - mean; s2 += d * d; }
    #pragma unroll
    for (int o = 32; o >= 1; o >>= 1) s2 += __shfl_xor(s2, o, 64);
    if (lane == 0) red[wid] = s2;
    __syncthreads();
    float var = (red[0] + red[1] + red[2] + red[3]) * (1.0f / 1024.0f);
    float rstd = rsqrtf(var + 1e-5f);
    #pragma unroll
    for (int i = 0; i < 4; ++i) {
        int c = tid + i * 256;
        out[(size_t)row * 1024 + c] = f2bf((x[i] - mean) * rstd * g[c] + bb[c]);
    }
}

// ---------------- layernorm (h + t_emb + add(bf16)) -> bf16 ----------------
__global__ __launch_bounds__(256) void ln_kernel(
    const float* __restrict__ hsrc, const float* __restrict__ trow,
    const short* __restrict__ add,
    const float* __restrict__ g, const float* __restrict__ bb,
    short* __restrict__ out)
{
    const int row = blockIdx.x;
    const int tid = threadIdx.x;
    const int lane = tid & 63;
    const int wid = tid >> 6;
    __shared__ float red[4];
    const float* hr = hsrc + (size_t)row * 1024;
    float x[4];
    float s = 0.f;
    #pragma unroll
    for (int i = 0; i < 4; ++i) {
        int c = tid + i * 256;
        float v = hr[c] + trow[c];
        if (add) v += bf2f(add[(size_t)row * 1024 + c]);
        x[i] = v; s += v;
    }
    #pragma unroll
    for (int o = 32; o >= 1; o >>= 1) s += __shfl_xor(s, o, 64);
    if (lane == 0) red[wid] = s;
    __syncthreads();
    float mean = (red[0] + red[1] + red[2] + red[3]) * (1.0f / 1024.0f);
    __syncthreads();
    float s2 = 0.f;
    #pragma unroll
    for (int i = 0; i < 4; ++i) { float d = x[i] - mean; s2 += d * d; }
    #pragma unroll
    for (int o = 32; o >= 1; o >>= 1) s2 += __shfl_xor(s2, o, 64);
    if (lane == 0) red[wid] = s2;
    __syncthreads();
    float var = (red[0] + red[1] + red[2] + red[3]) * (1.0f / 1024.0f);
    float rstd = rsqrtf(var + 1e-5f);
    #pragma unroll
    for (int i = 0; i < 4; ++i) {
        int c = tid + i * 256;
        out[(size_t)row * 1024 + c] = f2bf((x[i] - mean) * rstd * g[c] + bb[c]);
    }
}

// ---------------- fused clip(h += upd*scale) + LN(h_new + t_next) -> bf16 ----------------
__global__ __launch_bounds__(256) void clipln_kernel(
    const short* __restrict__ upd, float* __restrict__ h,
    const float* __restrict__ trow,
    const float* __restrict__ g, const float* __restrict__ bb,
    short* __restrict__ out)
{
    const int row = blockIdx.x;
    const int tid = threadIdx.x;
    const int lane = tid & 63;
    const int wid = tid >> 6;
    __shared__ float red[4];
    const short* ur = upd + (size_t)row * 1024;
    float u[4], hn[4];
    float s = 0.f;
    #pragma unroll
    for (int i = 0; i < 4; ++i) { u[i] = bf2f(ur[tid + i * 256]); s += u[i] * u[i]; }
    #pragma unroll
    for (int o = 32; o >= 1; o >>= 1) s += __shfl_xor(s, o, 64);
    if (lane == 0) red[wid] = s;
    __syncthreads();
    float nrm = sqrtf(red[0] + red[1] + red[2] + red[3]);
    float scale = fminf(1.0f / fmaxf(nrm, 1e-6f), 1.0f) * 0.125f;   // CLIP=1, /steps=8
    __syncthreads();
    float sm = 0.f;
    #pragma unroll
    for (int i = 0; i < 4; ++i) {
        int c = tid + i * 256;
        hn[i] = h[(size_t)row * 1024 + c] + u[i] * scale;
        h[(size_t)row * 1024 + c] = hn[i];
        hn[i] += trow[c];
        sm += hn[i];
    }
    #pragma unroll
    for (int o = 32; o >= 1; o >>= 1) sm += __shfl_xor(sm, o, 64);
    if (lane == 0) red[wid] = sm;
    __syncthreads();
    float mean = (red[0] + red[1] + red[2] + red[3]) * (1.0f / 1024.0f);
    __syncthreads();
    float s2 = 0.f;
    #pragma unroll
    for (int i = 0; i < 4; ++i) { float d = hn[i] - mean; s2 += d * d; }
    #pragma unroll
    for (int o = 32; o >= 1; o >>= 1) s2 += __shfl_xor(s2, o, 64);
    if (lane == 0) red[wid] = s2;
    __syncthreads();
    float var = (red[0] + red[1] + red[2] + red[3]) * (1.0f / 1024.0f);
    float rstd = rsqrtf(var + 1e-5f);
    #pragma unroll
    for (int i = 0; i < 4; ++i) {
        int c = tid + i * 256;
        out[(size_t)row * 1024 + c] = f2bf((hn[i] - mean) * rstd * g[c] + bb[c]);
    }
}

// ---------------- GEMM: C[M][N] = act(A[M][K] @ B[N][K]^T + bias) (+ addsrc bf16) ----------
// BMx128 tile, BK=64, 8 waves (512 thr), SINGLE-buffered LDS (m97 structure).
// LDS: BM=128 -> 32KB (3 blocks/CU at grid 768); BM=64 -> 24KB (4 blocks/CU at grid 1024).
// Cross-block TLP hides the barrier drain (m114); dbuf measured no better (R3/R7).
// BM=128: waves 4Mx2N (32x64 each). BM=64: waves 2Mx4N (32x32 each).
template<int BM, int ACT, int ADD, int BIAS>
__global__ __launch_bounds__(512) void gemm_kernel(
    const short* __restrict__ A, const short* __restrict__ B,
    const float* __restrict__ bias, const short* __restrict__ addsrc,
    short* __restrict__ Cout, int M, int N, int K)
{
    // XCD-chunked bijective block swizzle (all grids %8==0)
    const int nwg = gridDim.x * gridDim.y;
    const int orig = blockIdx.y * gridDim.x + blockIdx.x;
    const int swzid = (orig & 7) * (nwg >> 3) + (orig >> 3);
    const int bn = (swzid % gridDim.x) * 128;
    const int bm = (swzid / gridDim.x) * BM;

    __shared__ __align__(16) short As[BM * 64];
    __shared__ __align__(16) short Bs[128 * 64];
    const int tid = threadIdx.x;
    const int lane = tid & 63;
    const int wid = tid >> 6;           // 0..7
    const int l15 = lane & 15;
    const int l4 = lane >> 4;

    constexpr int MF = 2;
    constexpr int NF = (BM == 128) ? 4 : 2;
    const int rowbase = (BM == 128) ? (wid >> 1) * 32 : (wid >> 2) * 32;
    const int colbase = (BM == 128) ? (wid & 1) * 64 : (wid & 3) * 32;

    constexpr int ALOADS = BM * 8 / 512;            // 2 (BM=128) or 1 (BM=64)

    f32x4 acc[MF][NF];
    #pragma unroll
    for (int m = 0; m < MF; ++m)
        #pragma unroll
        for (int n = 0; n < NF; ++n)
            acc[m][n] = (f32x4)(0.f);

    const int nt = K >> 6;
    for (int t = 0; t < nt; ++t) {
        const int k0 = t << 6;
        #pragma unroll
        for (int i = 0; i < ALOADS; ++i) {
            int slot = i * 512 + tid;
            int row = slot >> 3;
            int colb = (slot & 7) * 16;
            int swz = (row & 7) << 4;
            const short* g = A + (size_t)(bm + row) * K + k0 + ((colb ^ swz) >> 1);
            gload_lds16(g, (short*)((char*)As + slot * 16));
        }
        #pragma unroll
        for (int i = 0; i < 2; ++i) {
            int slot = i * 512 + tid;
            int row = slot >> 3;
            int colb = (slot & 7) * 16;
            int swz = (row & 7) << 4;
            const short* g = B + (size_t)(bn + row) * K + k0 + ((colb ^ swz) >> 1);
            gload_lds16(g, (short*)((char*)Bs + slot * 16));
        }
        __syncthreads();   // drains vmcnt: staged tile visible
        #pragma unroll
        for (int ks = 0; ks < 2; ++ks) {
            int kb = ks * 64 + l4 * 16;
            bf16x8 a[MF], b[NF];
            #pragma unroll
            for (int m = 0; m < MF; ++m) {
                int row = rowbase + m * 16 + l15;
                a[m] = *(const bf16x8*)((const char*)As + row * 128 + (kb ^ ((row & 7) << 4)));
            }
            #pragma unroll
            for (int n = 0; n < NF; ++n) {
                int row = colbase + n * 16 + l15;
                b[n] = *(const bf16x8*)((const char*)Bs + row * 128 + (kb ^ ((row & 7) << 4)));
            }
            #pragma unroll
            for (int m = 0; m < MF; ++m)
                #pragma unroll
                for (int n = 0; n < NF; ++n)
                    acc[m][n] = __builtin_amdgcn_mfma_f32_16x16x32_bf16(a[m], b[n], acc[m][n], 0, 0, 0);
        }
        __syncthreads();   // all reads done before next-tile staging overwrites
    }

    #pragma unroll
    for (int m = 0; m < MF; ++m) {
        int row = bm + rowbase + m * 16 + l4 * 4;
        #pragma unroll
        for (int n = 0; n < NF; ++n) {
            int col = bn + colbase + n * 16 + l15;
            float bv = BIAS ? bias[col] : 0.f;
            #pragma unroll
            for (int r = 0; r < 4; ++r) {
                float v = acc[m][n][r] + bv;
                if (ACT) v = v / (1.f + __expf(-v));   // silu
                if (ADD) v += bf2f(addsrc[(size_t)(row + r) * N + col]);
                Cout[(size_t)(row + r) * N + col] = f2bf(v);
            }
        }
    }
}

// ---------------- attention: one block per (b,h); S=64, HD=64 ----------------
__global__ __launch_bounds__(256) void attn_kernel(
    const short* __restrict__ qkv,   // [4096][3072] bf16 (q|k|v)
    short* __restrict__ ctx)         // [4096][1024] bf16
{
    const int blk = blockIdx.x;      // b*16 + h
    const int b = blk >> 4, hh = blk & 15;
    const int bs0 = b * 64;
    __shared__ __align__(16) short qs[64 * 64];
    __shared__ __align__(16) short ks_[64 * 64];
    __shared__ __align__(16) short vt[64 * 64];   // transposed: vt[d][j]
    __shared__ __align__(16) short ps[64 * 64];
    const int tid = threadIdx.x;
    const int lane = tid & 63;
    const int wid = tid >> 6;
    const int l15 = lane & 15;
    const int l4 = lane >> 4;

    #pragma unroll
    for (int i = 0; i < 2; ++i) {
        int slot = i * 256 + tid;    // 0..511
        int row = slot >> 3;
        int colb = (slot & 7) * 16;
        int swz = (row & 7) << 4;
        const short* gq = qkv + (size_t)(bs0 + row) * 3072 + hh * 64 + (slot & 7) * 8;
        *(i32x4*)((char*)qs + row * 128 + (colb ^ swz)) = *(const i32x4*)gq;
        const short* gk = qkv + (size_t)(bs0 + row) * 3072 + 1024 + hh * 64 + (slot & 7) * 8;
        *(i32x4*)((char*)ks_ + row * 128 + (colb ^ swz)) = *(const i32x4*)gk;
        const short* gv = qkv + (size_t)(bs0 + row) * 3072 + 2048 + hh * 64 + (slot & 7) * 8;
        i32x4 vv = *(const i32x4*)gv;
        const short* ve = (const short*)&vv;
        #pragma unroll
        for (int j = 0; j < 8; ++j) {
            int d = (slot & 7) * 8 + j;
            *(short*)((char*)vt + d * 128 + ((row * 2) ^ ((d & 7) << 4))) = ve[j];
        }
    }
    __syncthreads();

    // scores: wave wid computes rows 16*wid..+15, all 64 cols
    f32x4 sc[4];
    #pragma unroll
    for (int n = 0; n < 4; ++n) sc[n] = (f32x4)(0.f);
    #pragma unroll
    for (int ksz = 0; ksz < 2; ++ksz) {
        int kb = ksz * 64 + l4 * 16;
        int arow = wid * 16 + l15;
        bf16x8 af = *(const bf16x8*)((const char*)qs + arow * 128 + (kb ^ ((arow & 7) << 4)));
        #pragma unroll
        for (int n = 0; n < 4; ++n) {
            int brow = n * 16 + l15;
            bf16x8 bf = *(const bf16x8*)((const char*)ks_ + brow * 128 + (kb ^ ((brow & 7) << 4)));
            sc[n] = __builtin_amdgcn_mfma_f32_16x16x32_bf16(af, bf, sc[n], 0, 0, 0);
        }
    }
    // softmax over cols; lane holds rows wid*16 + l4*4 + r, cols n*16 + l15
    float sm[4];
    #pragma unroll
    for (int r = 0; r < 4; ++r) {
        float m = -1e30f;
        #pragma unroll
        for (int n = 0; n < 4; ++n) { sc[n][r] *= 0.125f; m = fmaxf(m, sc[n][r]); }
        #pragma unroll
        for (int o = 1; o < 16; o <<= 1) m = fmaxf(m, __shfl_xor(m, o, 64));
        float s = 0.f;
        #pragma unroll
        for (int n = 0; n < 4; ++n) { sc[n][r] = __expf(sc[n][r] - m); s += sc[n][r]; }
        #pragma unroll
        for (int o = 1; o < 16; o <<= 1) s += __shfl_xor(s, o, 64);
        sm[r] = 1.f / s;
    }
    #pragma unroll
    for (int n = 0; n < 4; ++n)
        #pragma unroll
        for (int r = 0; r < 4; ++r) {
            int row = wid * 16 + l4 * 4 + r;
            int col = n * 16 + l15;
            *(short*)((char*)ps + row * 128 + ((col * 2) ^ ((row & 7) << 4))) = f2bf(sc[n][r] * sm[r]);
        }
    __syncthreads();

    // out = P @ V : A = ps (k = key idx), B[k][d] = vt[d][k]
    f32x4 o[4];
    #pragma unroll
    for (int n = 0; n < 4; ++n) o[n] = (f32x4)(0.f);
    #pragma unroll
    for (int ksz = 0; ksz < 2; ++ksz) {
        int kb = ksz * 64 + l4 * 16;
        int arow = wid * 16 + l15;
        bf16x8 af = *(const bf16x8*)((const char*)ps + arow * 128 + (kb ^ ((arow & 7) << 4)));
        #pragma unroll
        for (int n = 0; n < 4; ++n) {
            int vrow = n * 16 + l15;
            bf16x8 bf = *(const bf16x8*)((const char*)vt + vrow * 128 + (kb ^ ((vrow & 7) << 4)));
            o[n] = __builtin_amdgcn_mfma_f32_16x16x32_bf16(af, bf, o[n], 0, 0, 0);
        }
    }
    #pragma unroll
    for (int n = 0; n < 4; ++n)
        #pragma unroll
        for (int r = 0; r < 4; ++r) {
            int row = wid * 16 + l4 * 4 + r;
            int col = n * 16 + l15;
            ctx[(size_t)(bs0 + row) * 1024 + hh * 64 + col] = f2bf(o[n][r]);
        }
}

// ---------------- norm clip + h update (last step, no LN fusion) ----------------
__global__ __launch_bounds__(256) void clip_kernel(const short* __restrict__ upd, float* __restrict__ h) {
    const int row = blockIdx.x;
    const int tid = threadIdx.x;
    const int lane = tid & 63;
    const int wid = tid >> 6;
    __shared__ float red[4];
    const short* ur = upd + (size_t)row * 1024;
    float x[4];
    float s = 0.f;
    #pragma unroll
    for (int i = 0; i < 4; ++i) { x[i] = bf2f(ur[tid + i * 256]); s += x[i] * x[i]; }
    #pragma unroll
    for (int o = 32; o >= 1; o >>= 1) s += __shfl_xor(s, o, 64);
    if (lane == 0) red[wid] = s;
    __syncthreads();
    float nrm = sqrtf(red[0] + red[1] + red[2] + red[3]);
    float unorm = fmaxf(nrm, 1e-6f);
    float scale = fminf(1.0f / unorm, 1.0f) * 0.125f;   // CLIP=1, /steps=8
    #pragma unroll
    for (int i = 0; i < 4; ++i) {
        int c = tid + i * 256;
        h[(size_t)row * 1024 + c] += x[i] * scale;
    }
}

extern "C" void kernel_launch(void* const* d_in, const int* in_sizes, int n_in,
                              void* d_out, int out_size, void* d_ws, size_t ws_size,
                              hipStream_t stream) {
    const float* latents = (const float*)d_in[0];
    const float* t_table = (const float*)d_in[1];
    const float* attn_g  = (const float*)d_in[2];
    const float* attn_b  = (const float*)d_in[3];
    const float* ffn_g   = (const float*)d_in[4];
    const float* ffn_b   = (const float*)d_in[5];
    const float* Wq      = (const float*)d_in[6];
    const float* Wk      = (const float*)d_in[7];
    const float* Wv      = (const float*)d_in[8];
    const float* Wo      = (const float*)d_in[9];
    const float* Win     = (const float*)d_in[10];
    const float* b_in    = (const float*)d_in[11];
    const float* Wout    = (const float*)d_in[12];
    const float* b_out   = (const float*)d_in[13];

    char* ws = (char*)d_ws;
    size_t off = 0;
    auto alloc = [&](size_t bytes) { char* p = ws + off; off += (bytes + 255) & ~(size_t)255; return p; };
    short* wQKV = (short*)alloc((size_t)3072 * 1024 * 2);
    short* wO   = (short*)alloc((size_t)1024 * 1024 * 2);
    short* wIn  = (short*)alloc((size_t)2048 * 1024 * 2);
    short* wOut = (short*)alloc((size_t)1024 * 2048 * 2);
    short* xln  = (short*)alloc((size_t)4096 * 1024 * 2);
    short* qkv  = (short*)alloc((size_t)4096 * 3072 * 2);
    short* hidden = qkv;  // alias: qkv dead after attention, hidden born after
    short* ctx  = (short*)alloc((size_t)4096 * 1024 * 2);
    short* au   = (short*)alloc((size_t)4096 * 1024 * 2);   // bf16
    short* upd  = (short*)alloc((size_t)4096 * 1024 * 2);   // bf16

    float* h = (float*)d_out;   // h lives in d_out

    // all weights -> bf16 in one launch
    convert_all_kernel<<<2048, 256, 0, stream>>>(Wq, Wk, Wv, Wo, Win, Wout, wQKV, wO, wIn, wOut);
    // h = latents; xln = LN(latents + t0)
    first_ln_kernel<<<4096, 256, 0, stream>>>(latents, h, t_table, attn_g, attn_b, xln);

    for (int step = 0; step < 8; ++step) {
        const float* trow = t_table + (size_t)step * 1024;   // step <= 7 < T_EMB-1=8
        // qkv = xln @ WqkvT  [BM=128, 32KB LDS, grid 24x32=768 -> 3 blocks/CU exact]
        gemm_kernel<128, 0, 0, 0><<<dim3(24, 32), 512, 0, stream>>>(xln, wQKV, nullptr, nullptr, qkv, 4096, 3072, 1024);
        // attention -> ctx
        attn_kernel<<<1024, 256, 0, stream>>>(qkv, ctx);
        // attn_update = ctx @ WoT -> au (bf16)  [BM=64, 24KB, grid 8x64=512]
        gemm_kernel<64, 0, 0, 0><<<dim3(8, 64), 512, 0, stream>>>(ctx, wO, nullptr, nullptr, au, 4096, 1024, 1024);
        // ffn_in = LN(h + t + au) -> xln (bf16, reuse)
        ln_kernel<<<4096, 256, 0, stream>>>(h, trow, au, ffn_g, ffn_b, xln);
        // hidden = silu(xln @ WinT + b_in) (bf16)  [BM=64, grid 16x64=1024 -> 4 blocks/CU]
        gemm_kernel<64, 1, 0, 1><<<dim3(16, 64), 512, 0, stream>>>(xln, wIn, b_in, nullptr, hidden, 4096, 2048, 1024);
        // upd = hidden @ WoutT + b_out + au (bf16)  [BM=64, grid 8x64=512]
        gemm_kernel<64, 0, 1, 1><<<dim3(8, 64), 512, 0, stream>>>(hidden, wOut, b_out, au, upd, 4096, 1024, 2048);
        if (step < 7) {
            // h += clip(upd)/8, then LN1 of next step -> xln
            clipln_kernel<<<4096, 256, 0, stream>>>(upd, h, t_table + (size_t)(step + 1) * 1024,
                                                    attn_g, attn_b, xln);
        } else {
            clip_kernel<<<4096, 256, 0, stream>>>(upd, h);
        }
    }
}